// Round 1
// baseline (1565.999 us; speedup 1.0000x reference)
//
#include <hip/hip_runtime.h>
#include <math.h>

#define E_EDGES 320000
#define NN 20000
#define NG 64
#define D 128
#define DA 16
#define HID 256
#define K1PAD 544   // 528 padded to 17*32

typedef _Float16 f16;
typedef _Float16 v8h __attribute__((ext_vector_type(8)));
typedef float v4f __attribute__((ext_vector_type(4)));

__device__ __forceinline__ unsigned fkey(float f) {
  unsigned u = __float_as_uint(f);
  return (u & 0x80000000u) ? ~u : (u | 0x80000000u);
}
__device__ __forceinline__ float fdec(unsigned k) {
  return (k & 0x80000000u) ? __uint_as_float(k & 0x7fffffffu) : __uint_as_float(~k);
}

// per-node precompute: 6 dot products with W_agg/W_upd/W_read x-slices, plus x -> f16
__global__ __launch_bounds__(256) void k_prep_nodes(
    const float* __restrict__ x, const float* __restrict__ Wagg,
    const float* __restrict__ Wupd, const float* __restrict__ Wread,
    f16* __restrict__ xh, float* __restrict__ na1, float* __restrict__ na2,
    float* __restrict__ nu1, float* __restrict__ nu2,
    float* __restrict__ nr1, float* __restrict__ nr2) {
  int t = threadIdx.x, lane = t & 63;
  int n = blockIdx.x * 4 + (t >> 6);
  float x1 = x[n * D + lane], x2 = x[n * D + 64 + lane];
  xh[n * D + lane] = (f16)x1;
  xh[n * D + 64 + lane] = (f16)x2;
  float pa1 = x1 * Wagg[lane] + x2 * Wagg[64 + lane];
  float pa2 = x1 * Wagg[128 + lane] + x2 * Wagg[192 + lane];
  float pu1 = x1 * Wupd[lane] + x2 * Wupd[64 + lane];
  float pu2 = x1 * Wupd[128 + lane] + x2 * Wupd[192 + lane];
  float pr1 = x1 * Wread[lane] + x2 * Wread[64 + lane];
  float pr2 = x1 * Wread[128 + lane] + x2 * Wread[192 + lane];
  for (int o = 32; o > 0; o >>= 1) {
    pa1 += __shfl_xor(pa1, o); pa2 += __shfl_xor(pa2, o);
    pu1 += __shfl_xor(pu1, o); pu2 += __shfl_xor(pu2, o);
    pr1 += __shfl_xor(pr1, o); pr2 += __shfl_xor(pr2, o);
  }
  if (lane == 0) {
    na1[n] = pa1; na2[n] = pa2; nu1[n] = pu1;
    nu2[n] = pu2; nr1[n] = pr1; nr2[n] = pr2;
  }
}

// W1 (528x256, zero-pad to 544) and W2 (256x128) -> f16, B-fragment-swizzled [k>>3][n][k&7]
__global__ __launch_bounds__(256) void k_prep_w(
    const float* __restrict__ W1, const float* __restrict__ W2,
    f16* __restrict__ W1s, f16* __restrict__ W2s) {
  int blk = blockIdx.x, t = threadIdx.x;
  if (blk < K1PAD) {
    int k = blk;
    float v = (k < 528) ? W1[k * HID + t] : 0.f;
    W1s[((k >> 3) * HID + t) * 8 + (k & 7)] = (f16)v;
  } else {
    int k = blk - K1PAD;
    if (t < D) W2s[((k >> 3) * D + t) * 8 + (k & 7)] = (f16)W2[k * D + t];
  }
}

// per-edge: logits bases, gidx, attr -> f16 (padded 32), node segment-max of agg logits
__global__ __launch_bounds__(256) void k_prep_edges(
    const float* __restrict__ hef, const float* __restrict__ attr,
    const int* __restrict__ rol, const int* __restrict__ col,
    const int* __restrict__ batch,
    const float* __restrict__ Wagg, const float* __restrict__ bagg,
    const float* __restrict__ Wupd, const float* __restrict__ bupd,
    const float* __restrict__ Wread, const float* __restrict__ bread,
    const float* __restrict__ na1, const float* __restrict__ na2,
    const float* __restrict__ nu1, const float* __restrict__ nu2,
    const float* __restrict__ nr1, const float* __restrict__ nr2,
    float* __restrict__ agg_logit, float* __restrict__ upd_base,
    float* __restrict__ read_base, int* __restrict__ gidx,
    unsigned* __restrict__ m_node, f16* __restrict__ attrh) {
  int t = threadIdx.x, lane = t & 63;
  int e = blockIdx.x * 4 + (t >> 6);
  float h1 = hef[e * D + lane], h2 = hef[e * D + 64 + lane];
  float at = 0.f;
  float pa = h1 * Wagg[272 + lane] + h2 * Wagg[336 + lane];
  float pu = h1 * Wupd[272 + lane] + h2 * Wupd[336 + lane];
  float pr = 0.f;
  if (lane < DA) {
    at = attr[e * DA + lane];
    pa += at * Wagg[256 + lane];
    pu += at * Wupd[256 + lane];
    pr = at * Wread[384 + lane];
  }
  if (lane < 32) attrh[e * 32 + lane] = (f16)at;  // lanes 16..31 write zero pad
  for (int o = 32; o > 0; o >>= 1) {
    pa += __shfl_xor(pa, o); pu += __shfl_xor(pu, o); pr += __shfl_xor(pr, o);
  }
  if (lane == 0) {
    int r = rol[e], c = col[e];
    float la = na1[r] + na2[c] + pa + bagg[0];
    agg_logit[e] = la;
    upd_base[e] = nu1[r] + nu2[c] + pu + bupd[0];
    read_base[e] = nr1[r] + nr2[c] + pr + bread[0];
    gidx[e] = batch[r];
    atomicMax(&m_node[c], fkey(la));
  }
}

// exp + segment-sum + weighted scatter of hef into node_feat_raw (unnormalized)
__global__ __launch_bounds__(256) void k_scatter_nf(
    const float* __restrict__ hef, const int* __restrict__ col,
    const float* __restrict__ agg_logit, const unsigned* __restrict__ m_node,
    float* __restrict__ s_node, float* __restrict__ nf_raw) {
  int t = threadIdx.x, lane = t & 63;
  int e = blockIdx.x * 4 + (t >> 6);
  int c = col[e];
  float v = expf(agg_logit[e] - fdec(m_node[c]));
  if (lane == 0) atomicAdd(&s_node[c], v);
  atomicAdd(&nf_raw[c * D + lane], v * hef[e * D + lane]);
  atomicAdd(&nf_raw[c * D + 64 + lane], v * hef[e * D + 64 + lane]);
}

// normalize node_feat, store f16
__global__ __launch_bounds__(256) void k_norm_nf(
    const float* __restrict__ nf_raw, const float* __restrict__ s_node,
    f16* __restrict__ nfh) {
  int i = blockIdx.x * 256 + threadIdx.x;
  int n = i >> 7;
  nfh[i] = (f16)(nf_raw[i] / (s_node[n] + 1e-16f));
}

// fused MLP (MFMA f16) + gate + mix + readout logit. 64 edges/block, 4 waves.
// GEMM1: A(64x544) gathered from xh/nfh/attrh, B=W1s -> hidden(64x256) relu -> LDS (f16, A-frag layout)
// GEMM2: hidden @ W2s -> cand(64x128) -> LDS f32 -> epilogue
__global__ __launch_bounds__(256, 2) void k_mlp(
    const f16* __restrict__ xh, const f16* __restrict__ nfh,
    const f16* __restrict__ attrh,
    const f16* __restrict__ W1s, const f16* __restrict__ W2s,
    const float* __restrict__ b1, const float* __restrict__ b2,
    const int* __restrict__ rol, const int* __restrict__ col,
    const float* __restrict__ hef,
    const float* __restrict__ Wupd, const float* __restrict__ Wread,
    const float* __restrict__ upd_base, const float* __restrict__ read_base,
    const int* __restrict__ gidx,
    float* __restrict__ out_ef, float* __restrict__ read_logit,
    unsigned* __restrict__ m_graph) {
  __shared__ float sbuf[64 * 130];      // 33.3 KB; first 32 KB doubles as f16 hidden
  f16* hl = (f16*)sbuf;

  int t = threadIdx.x;
  int w = t >> 6, lane = t & 63;
  int q = lane >> 4, m16 = lane & 15;
  int eb = blockIdx.x * 64;

  int rr[4], cc[4], em[4];
#pragma unroll
  for (int mt = 0; mt < 4; ++mt) {
    em[mt] = eb + mt * 16 + m16;
    rr[mt] = rol[em[mt]];
    cc[mt] = col[em[mt]];
  }

  v4f acc1[4][4];
#pragma unroll
  for (int i = 0; i < 4; i++)
#pragma unroll
    for (int j = 0; j < 4; j++) acc1[i][j] = (v4f){0.f, 0.f, 0.f, 0.f};

  const v8h* w1v = (const v8h*)W1s;

  for (int c = 0; c < 17; ++c) {
    v8h a[4], b[4];
    if (c < 16) {
      int bb = c >> 2;
      const f16* tab = (bb == 0 || bb == 2) ? xh : nfh;
      int off = (c & 3) * 32 + q * 8;
#pragma unroll
      for (int mt = 0; mt < 4; ++mt) {
        int node = (bb < 2) ? rr[mt] : cc[mt];
        a[mt] = *(const v8h*)(tab + node * D + off);
      }
    } else {
#pragma unroll
      for (int mt = 0; mt < 4; ++mt)
        a[mt] = *(const v8h*)(attrh + em[mt] * 32 + q * 8);
    }
    int brow = c * 4 + q;
#pragma unroll
    for (int nt = 0; nt < 4; ++nt)
      b[nt] = w1v[brow * HID + (w * 4 + nt) * 16 + m16];
#pragma unroll
    for (int mt = 0; mt < 4; ++mt)
#pragma unroll
      for (int nt = 0; nt < 4; ++nt)
        acc1[mt][nt] = __builtin_amdgcn_mfma_f32_16x16x32_f16(a[mt], b[nt], acc1[mt][nt], 0, 0, 0);
  }

  // bias + relu, store hidden to LDS in A-fragment layout [k>>3][m][k&7]
#pragma unroll
  for (int nt = 0; nt < 4; ++nt) {
    int n = (w * 4 + nt) * 16 + m16;
    float bv = b1[n];
    int nhi = n >> 3, nlo = n & 7;
#pragma unroll
    for (int mt = 0; mt < 4; ++mt)
#pragma unroll
      for (int r = 0; r < 4; ++r) {
        int m = mt * 16 + q * 4 + r;
        float h = acc1[mt][nt][r] + bv;
        hl[(nhi * 64 + m) * 8 + nlo] = (f16)fmaxf(h, 0.f);
      }
  }
  __syncthreads();

  const v8h* w2v = (const v8h*)W2s;
  const v8h* hlv = (const v8h*)hl;
  v4f acc2[4][2];
#pragma unroll
  for (int i = 0; i < 4; i++) {
    acc2[i][0] = (v4f){0.f, 0.f, 0.f, 0.f};
    acc2[i][1] = (v4f){0.f, 0.f, 0.f, 0.f};
  }
  for (int kc = 0; kc < 8; ++kc) {
    int krow = kc * 4 + q;
    v8h a2[4], b2f[2];
#pragma unroll
    for (int mt = 0; mt < 4; ++mt) a2[mt] = hlv[krow * 64 + mt * 16 + m16];
#pragma unroll
    for (int nt = 0; nt < 2; ++nt) b2f[nt] = w2v[krow * D + (w * 2 + nt) * 16 + m16];
#pragma unroll
    for (int mt = 0; mt < 4; ++mt)
#pragma unroll
      for (int nt = 0; nt < 2; ++nt)
        acc2[mt][nt] = __builtin_amdgcn_mfma_f32_16x16x32_f16(a2[mt], b2f[nt], acc2[mt][nt], 0, 0, 0);
  }
  __syncthreads();

  // cand f32 -> LDS (stride 130 to dodge bank conflicts)
#pragma unroll
  for (int nt = 0; nt < 2; ++nt) {
    int n = (w * 2 + nt) * 16 + m16;
    float bv = b2[n];
#pragma unroll
    for (int mt = 0; mt < 4; ++mt)
#pragma unroll
      for (int r = 0; r < 4; ++r) {
        int m = mt * 16 + q * 4 + r;
        sbuf[m * 130 + n] = acc2[mt][nt][r] + bv;
      }
  }
  __syncthreads();

  // epilogue: 4 threads per edge row
  {
    int m = t >> 2, sub = t & 3;
    int e = eb + m;
    float ub = upd_base[e], rb = read_base[e];
    int g = gidx[e];
    v4f cv[8];
    float dg = 0.f;
#pragma unroll
    for (int i = 0; i < 8; ++i) {
      int co = sub * 32 + i * 4;
      cv[i] = *(const v4f*)(sbuf + m * 130 + co);
      v4f wu = *(const v4f*)(Wupd + 400 + co);
      dg += cv[i][0] * wu[0] + cv[i][1] * wu[1] + cv[i][2] * wu[2] + cv[i][3] * wu[3];
    }
    dg += __shfl_xor(dg, 1);
    dg += __shfl_xor(dg, 2);
    float gt = 1.f / (1.f + expf(-(ub + dg)));
    float dr = 0.f;
#pragma unroll
    for (int i = 0; i < 8; ++i) {
      int co = sub * 32 + i * 4;
      v4f h4 = *(const v4f*)(hef + (long)e * D + co);
      v4f ef;
      ef[0] = gt * cv[i][0] + (1.f - gt) * h4[0];
      ef[1] = gt * cv[i][1] + (1.f - gt) * h4[1];
      ef[2] = gt * cv[i][2] + (1.f - gt) * h4[2];
      ef[3] = gt * cv[i][3] + (1.f - gt) * h4[3];
      *(v4f*)(out_ef + (long)e * D + co) = ef;
      v4f wr = *(const v4f*)(Wread + 256 + co);
      dr += ef[0] * wr[0] + ef[1] * wr[1] + ef[2] * wr[2] + ef[3] * wr[3];
    }
    dr += __shfl_xor(dr, 1);
    dr += __shfl_xor(dr, 2);
    if (sub == 0) {
      float lg = rb + dr;
      read_logit[e] = lg;
      atomicMax(&m_graph[g], fkey(lg));
    }
  }
}

// graph softmax accumulate: per-block LDS [64][128] partials, then global atomics
__global__ __launch_bounds__(256) void k_readout(
    const float* __restrict__ ef, const float* __restrict__ read_logit,
    const int* __restrict__ gidx, const unsigned* __restrict__ m_graph,
    float* __restrict__ s_graph, float* __restrict__ graph_raw) {
  __shared__ float accg[NG * D];
  __shared__ float sg[NG];
  int t = threadIdx.x;
  for (int j = t; j < NG * D; j += 256) accg[j] = 0.f;
  if (t < NG) sg[t] = 0.f;
  __syncthreads();
  int base = blockIdx.x * 1250;
  int half = t >> 7, d = t & 127;
  for (int i = 0; i < 625; ++i) {
    int e = base + i * 2 + half;
    float l = read_logit[e];
    int g = gidx[e];
    float wv = expf(l - fdec(m_graph[g]));
    if (d == 0) atomicAdd(&sg[g], wv);
    atomicAdd(&accg[g * D + d], wv * ef[(long)e * D + d]);
  }
  __syncthreads();
  for (int j = t; j < NG * D; j += 256) atomicAdd(&graph_raw[j], accg[j]);
  if (t < NG) atomicAdd(&s_graph[t], sg[t]);
}

__global__ __launch_bounds__(64) void k_conf(
    const float* __restrict__ graph_raw, const float* __restrict__ s_graph,
    const float* __restrict__ Wscore, const float* __restrict__ bscore,
    float* __restrict__ out_conf) {
  int g = blockIdx.x, d = threadIdx.x;
  float s = s_graph[g] + 1e-16f;
  float v1 = graph_raw[g * D + d] / s;
  float v2 = graph_raw[g * D + 64 + d] / s;
  float p = v1 * Wscore[d] + v2 * Wscore[64 + d];
  for (int o = 32; o > 0; o >>= 1) p += __shfl_xor(p, o);
  if (d == 0) out_conf[g] = 1.f / (1.f + expf(-(p + bscore[0])));
}

extern "C" void kernel_launch(void* const* d_in, const int* in_sizes, int n_in,
                              void* d_out, int out_size, void* d_ws, size_t ws_size,
                              hipStream_t stream) {
  const float* x = (const float*)d_in[0];
  const float* hef = (const float*)d_in[1];
  const float* attr = (const float*)d_in[2];
  const int* eidx = (const int*)d_in[3];
  const int* rol = eidx;
  const int* col = eidx + E_EDGES;
  const int* batch = (const int*)d_in[4];
  const float* Wagg = (const float*)d_in[6];
  const float* bagg = (const float*)d_in[7];
  const float* W1 = (const float*)d_in[8];
  const float* b1 = (const float*)d_in[9];
  const float* W2 = (const float*)d_in[10];
  const float* b2 = (const float*)d_in[11];
  const float* Wupd = (const float*)d_in[12];
  const float* bupd = (const float*)d_in[13];
  const float* Wread = (const float*)d_in[14];
  const float* bread = (const float*)d_in[15];
  const float* Wscore = (const float*)d_in[16];
  const float* bscore = (const float*)d_in[17];

  char* ws = (char*)d_ws;
  size_t off = 0;
  auto alloc = [&](size_t bytes) -> void* {
    void* p = ws + off;
    off = (off + bytes + 255) & ~(size_t)255;
    return p;
  };

  // zero-initialized region first (single memset)
  unsigned* m_node = (unsigned*)alloc(NN * 4);
  float* s_node = (float*)alloc(NN * 4);
  float* nf_raw = (float*)alloc((size_t)NN * D * 4);
  unsigned* m_graph = (unsigned*)alloc(NG * 4);
  float* s_graph = (float*)alloc(NG * 4);
  float* graph_raw = (float*)alloc(NG * D * 4);
  size_t zero_bytes = off;

  f16* xh = (f16*)alloc((size_t)NN * D * 2);
  f16* nfh = (f16*)alloc((size_t)NN * D * 2);
  f16* attrh = (f16*)alloc((size_t)E_EDGES * 32 * 2);
  f16* W1s = (f16*)alloc((size_t)K1PAD * HID * 2);
  f16* W2s = (f16*)alloc((size_t)HID * D * 2);
  float* na1 = (float*)alloc(NN * 4);
  float* na2 = (float*)alloc(NN * 4);
  float* nu1 = (float*)alloc(NN * 4);
  float* nu2 = (float*)alloc(NN * 4);
  float* nr1 = (float*)alloc(NN * 4);
  float* nr2 = (float*)alloc(NN * 4);
  float* agg_logit = (float*)alloc((size_t)E_EDGES * 4);
  float* upd_base = (float*)alloc((size_t)E_EDGES * 4);
  float* read_base = (float*)alloc((size_t)E_EDGES * 4);
  float* read_logit = (float*)alloc((size_t)E_EDGES * 4);
  int* gidx = (int*)alloc((size_t)E_EDGES * 4);

  float* out_ef = (float*)d_out;
  float* out_conf = out_ef + (size_t)E_EDGES * D;

  hipMemsetAsync(d_ws, 0, zero_bytes, stream);
  k_prep_nodes<<<NN / 4, 256, 0, stream>>>(x, Wagg, Wupd, Wread, xh, na1, na2, nu1, nu2, nr1, nr2);
  k_prep_w<<<K1PAD + HID, 256, 0, stream>>>(W1, W2, W1s, W2s);
  k_prep_edges<<<E_EDGES / 4, 256, 0, stream>>>(hef, attr, rol, col, batch,
      Wagg, bagg, Wupd, bupd, Wread, bread,
      na1, na2, nu1, nu2, nr1, nr2,
      agg_logit, upd_base, read_base, gidx, m_node, attrh);
  k_scatter_nf<<<E_EDGES / 4, 256, 0, stream>>>(hef, col, agg_logit, m_node, s_node, nf_raw);
  k_norm_nf<<<(NN * D) / 256, 256, 0, stream>>>(nf_raw, s_node, nfh);
  k_mlp<<<E_EDGES / 64, 256, 0, stream>>>(xh, nfh, attrh, W1s, W2s, b1, b2,
      rol, col, hef, Wupd, Wread, upd_base, read_base, gidx,
      out_ef, read_logit, m_graph);
  k_readout<<<256, 256, 0, stream>>>(out_ef, read_logit, gidx, m_graph, s_graph, graph_raw);
  k_conf<<<NG, 64, 0, stream>>>(graph_raw, s_graph, Wscore, bscore, out_conf);
}

// Round 2
// 1206.681 us; speedup vs baseline: 1.2978x; 1.2978x over previous
//
#include <hip/hip_runtime.h>
#include <math.h>
#include <float.h>

#define E_EDGES 320000
#define NN 20000
#define NG 64
#define D 128
#define DA 16
#define HID 256
#define K1PAD 544   // 528 padded to 17*32
#define RB 256      // readout blocks

typedef _Float16 f16;
typedef _Float16 v8h __attribute__((ext_vector_type(8)));
typedef float v4f __attribute__((ext_vector_type(4)));

__device__ __forceinline__ unsigned fkey(float f) {
  unsigned u = __float_as_uint(f);
  return (u & 0x80000000u) ? ~u : (u | 0x80000000u);
}
__device__ __forceinline__ float fdec(unsigned k) {
  return (k & 0x80000000u) ? __uint_as_float(k & 0x7fffffffu) : __uint_as_float(~k);
}

// per-node precompute: 6 dot products with W_agg/W_upd/W_read x-slices, plus x -> f16
__global__ __launch_bounds__(256) void k_prep_nodes(
    const float* __restrict__ x, const float* __restrict__ Wagg,
    const float* __restrict__ Wupd, const float* __restrict__ Wread,
    f16* __restrict__ xh, float* __restrict__ na1, float* __restrict__ na2,
    float* __restrict__ nu1, float* __restrict__ nu2,
    float* __restrict__ nr1, float* __restrict__ nr2) {
  int t = threadIdx.x, lane = t & 63;
  int n = blockIdx.x * 4 + (t >> 6);
  float x1 = x[n * D + lane], x2 = x[n * D + 64 + lane];
  xh[n * D + lane] = (f16)x1;
  xh[n * D + 64 + lane] = (f16)x2;
  float pa1 = x1 * Wagg[lane] + x2 * Wagg[64 + lane];
  float pa2 = x1 * Wagg[128 + lane] + x2 * Wagg[192 + lane];
  float pu1 = x1 * Wupd[lane] + x2 * Wupd[64 + lane];
  float pu2 = x1 * Wupd[128 + lane] + x2 * Wupd[192 + lane];
  float pr1 = x1 * Wread[lane] + x2 * Wread[64 + lane];
  float pr2 = x1 * Wread[128 + lane] + x2 * Wread[192 + lane];
  for (int o = 32; o > 0; o >>= 1) {
    pa1 += __shfl_xor(pa1, o); pa2 += __shfl_xor(pa2, o);
    pu1 += __shfl_xor(pu1, o); pu2 += __shfl_xor(pu2, o);
    pr1 += __shfl_xor(pr1, o); pr2 += __shfl_xor(pr2, o);
  }
  if (lane == 0) {
    na1[n] = pa1; na2[n] = pa2; nu1[n] = pu1;
    nu2[n] = pu2; nr1[n] = pr1; nr2[n] = pr2;
  }
}

// W1 (528x256, zero-pad to 544) and W2 (256x128) -> f16, B-fragment-swizzled [k>>3][n][k&7]
__global__ __launch_bounds__(256) void k_prep_w(
    const float* __restrict__ W1, const float* __restrict__ W2,
    f16* __restrict__ W1s, f16* __restrict__ W2s) {
  int blk = blockIdx.x, t = threadIdx.x;
  if (blk < K1PAD) {
    int k = blk;
    float v = (k < 528) ? W1[k * HID + t] : 0.f;
    W1s[((k >> 3) * HID + t) * 8 + (k & 7)] = (f16)v;
  } else {
    int k = blk - K1PAD;
    if (t < D) W2s[((k >> 3) * D + t) * 8 + (k & 7)] = (f16)W2[k * D + t];
  }
}

// per-edge: logit bases, gidx, attr -> f16 (padded 32), degree count for CSR
__global__ __launch_bounds__(256) void k_prep_edges(
    const float* __restrict__ hef, const float* __restrict__ attr,
    const int* __restrict__ rol, const int* __restrict__ col,
    const int* __restrict__ batch,
    const float* __restrict__ Wagg, const float* __restrict__ bagg,
    const float* __restrict__ Wupd, const float* __restrict__ bupd,
    const float* __restrict__ Wread, const float* __restrict__ bread,
    const float* __restrict__ na1, const float* __restrict__ na2,
    const float* __restrict__ nu1, const float* __restrict__ nu2,
    const float* __restrict__ nr1, const float* __restrict__ nr2,
    float* __restrict__ agg_logit, float* __restrict__ upd_base,
    float* __restrict__ read_base, int* __restrict__ gidx,
    int* __restrict__ deg, f16* __restrict__ attrh) {
  int t = threadIdx.x, lane = t & 63;
  int e = blockIdx.x * 4 + (t >> 6);
  float h1 = hef[e * D + lane], h2 = hef[e * D + 64 + lane];
  float at = 0.f;
  float pa = h1 * Wagg[272 + lane] + h2 * Wagg[336 + lane];
  float pu = h1 * Wupd[272 + lane] + h2 * Wupd[336 + lane];
  float pr = 0.f;
  if (lane < DA) {
    at = attr[e * DA + lane];
    pa += at * Wagg[256 + lane];
    pu += at * Wupd[256 + lane];
    pr = at * Wread[384 + lane];
  }
  if (lane < 32) attrh[e * 32 + lane] = (f16)at;  // lanes 16..31 write zero pad
  for (int o = 32; o > 0; o >>= 1) {
    pa += __shfl_xor(pa, o); pu += __shfl_xor(pu, o); pr += __shfl_xor(pr, o);
  }
  if (lane == 0) {
    int r = rol[e], c = col[e];
    agg_logit[e] = na1[r] + na2[c] + pa + bagg[0];
    upd_base[e] = nu1[r] + nu2[c] + pu + bupd[0];
    read_base[e] = nr1[r] + nr2[c] + pr + bread[0];
    gidx[e] = batch[r];
    atomicAdd(&deg[c], 1);
  }
}

// single-block prefix sum: deg -> rowptr (exclusive in cursor, inclusive shifted in rowptr)
__global__ __launch_bounds__(1024) void k_scan(
    const int* __restrict__ deg, int* __restrict__ rowptr, int* __restrict__ cursor) {
  __shared__ int buf[1024];
  __shared__ int carry_s;
  int t = threadIdx.x;
  if (t == 0) { carry_s = 0; rowptr[0] = 0; }
  __syncthreads();
  for (int c = 0; c < 20; ++c) {
    int idx = c * 1024 + t;
    int v = (idx < NN) ? deg[idx] : 0;
    buf[t] = v;
    __syncthreads();
    for (int o = 1; o < 1024; o <<= 1) {
      int x = (t >= o) ? buf[t - o] : 0;
      __syncthreads();
      buf[t] += x;
      __syncthreads();
    }
    int incl = buf[t];
    int carry = carry_s;
    __syncthreads();
    if (t == 1023) carry_s = carry + incl;
    if (idx < NN) { rowptr[idx + 1] = carry + incl; cursor[idx] = carry + incl - v; }
    __syncthreads();
  }
}

__global__ __launch_bounds__(256) void k_csr_fill(
    const int* __restrict__ col, int* __restrict__ cursor, int* __restrict__ csr) {
  int e = blockIdx.x * 256 + threadIdx.x;
  int c = col[e];
  int slot = atomicAdd(&cursor[c], 1);
  csr[slot] = e;
}

// one wave per node: segment softmax + weighted gather of hef rows -> nfh (f16, normalized)
__global__ __launch_bounds__(256) void k_node_feat(
    const int* __restrict__ rowptr, const int* __restrict__ csr,
    const float* __restrict__ agg_logit, const float* __restrict__ hef,
    f16* __restrict__ nfh) {
  int t = threadIdx.x, lane = t & 63, w = t >> 6;
  int n = blockIdx.x * 4 + w;
  int b0 = rowptr[n], b1 = rowptr[n + 1], dg = b1 - b0;
  float m = -FLT_MAX;
  for (int i = lane; i < dg; i += 64) m = fmaxf(m, agg_logit[csr[b0 + i]]);
  for (int o = 32; o > 0; o >>= 1) m = fmaxf(m, __shfl_xor(m, o));
  float s = 0.f, a0 = 0.f, a1 = 0.f;
  for (int d = 0; d < dg; ++d) {
    int e = csr[b0 + d];                       // uniform -> scalar broadcast load
    float wv = expf(agg_logit[e] - m);
    s += wv;
    a0 += wv * hef[(long)e * D + lane];
    a1 += wv * hef[(long)e * D + 64 + lane];
  }
  float inv = 1.f / (s + 1e-16f);
  nfh[n * D + lane] = (f16)(a0 * inv);
  nfh[n * D + 64 + lane] = (f16)(a1 * inv);
}

// fused MLP (MFMA f16) + gate + mix + readout logit. 64 edges/block, 4 waves.
__global__ __launch_bounds__(256, 4) void k_mlp(
    const f16* __restrict__ xh, const f16* __restrict__ nfh,
    const f16* __restrict__ attrh,
    const f16* __restrict__ W1s, const f16* __restrict__ W2s,
    const float* __restrict__ b1, const float* __restrict__ b2,
    const int* __restrict__ rol, const int* __restrict__ col,
    const float* __restrict__ hef,
    const float* __restrict__ Wupd, const float* __restrict__ Wread,
    const float* __restrict__ upd_base, const float* __restrict__ read_base,
    float* __restrict__ out_ef, float* __restrict__ read_logit) {
  __shared__ float sbuf[64 * 130];      // 33.3 KB; first 32 KB doubles as f16 hidden
  f16* hl = (f16*)sbuf;

  int t = threadIdx.x;
  int w = t >> 6, lane = t & 63;
  int q = lane >> 4, m16 = lane & 15;
  int eb = blockIdx.x * 64;

  int rr[4], cc[4], em[4];
#pragma unroll
  for (int mt = 0; mt < 4; ++mt) {
    em[mt] = eb + mt * 16 + m16;
    rr[mt] = rol[em[mt]];
    cc[mt] = col[em[mt]];
  }

  v4f acc1[4][4];
#pragma unroll
  for (int i = 0; i < 4; i++)
#pragma unroll
    for (int j = 0; j < 4; j++) acc1[i][j] = (v4f){0.f, 0.f, 0.f, 0.f};

  const v8h* w1v = (const v8h*)W1s;

  for (int c = 0; c < 17; ++c) {
    v8h a[4], b[4];
    if (c < 16) {
      int bb = c >> 2;
      const f16* tab = (bb == 0 || bb == 2) ? xh : nfh;
      int off = (c & 3) * 32 + q * 8;
#pragma unroll
      for (int mt = 0; mt < 4; ++mt) {
        int node = (bb < 2) ? rr[mt] : cc[mt];
        a[mt] = *(const v8h*)(tab + node * D + off);
      }
    } else {
#pragma unroll
      for (int mt = 0; mt < 4; ++mt)
        a[mt] = *(const v8h*)(attrh + em[mt] * 32 + q * 8);
    }
    int brow = c * 4 + q;
#pragma unroll
    for (int nt = 0; nt < 4; ++nt)
      b[nt] = w1v[brow * HID + (w * 4 + nt) * 16 + m16];
#pragma unroll
    for (int mt = 0; mt < 4; ++mt)
#pragma unroll
      for (int nt = 0; nt < 4; ++nt)
        acc1[mt][nt] = __builtin_amdgcn_mfma_f32_16x16x32_f16(a[mt], b[nt], acc1[mt][nt], 0, 0, 0);
  }

  // bias + relu, store hidden to LDS in A-fragment layout [k>>3][m][k&7]
#pragma unroll
  for (int nt = 0; nt < 4; ++nt) {
    int n = (w * 4 + nt) * 16 + m16;
    float bv = b1[n];
    int nhi = n >> 3, nlo = n & 7;
#pragma unroll
    for (int mt = 0; mt < 4; ++mt)
#pragma unroll
      for (int r = 0; r < 4; ++r) {
        int m = mt * 16 + q * 4 + r;
        float h = acc1[mt][nt][r] + bv;
        hl[(nhi * 64 + m) * 8 + nlo] = (f16)fmaxf(h, 0.f);
      }
  }
  __syncthreads();

  const v8h* w2v = (const v8h*)W2s;
  const v8h* hlv = (const v8h*)hl;
  v4f acc2[4][2];
#pragma unroll
  for (int i = 0; i < 4; i++) {
    acc2[i][0] = (v4f){0.f, 0.f, 0.f, 0.f};
    acc2[i][1] = (v4f){0.f, 0.f, 0.f, 0.f};
  }
  for (int kc = 0; kc < 8; ++kc) {
    int krow = kc * 4 + q;
    v8h a2[4], b2f[2];
#pragma unroll
    for (int mt = 0; mt < 4; ++mt) a2[mt] = hlv[krow * 64 + mt * 16 + m16];
#pragma unroll
    for (int nt = 0; nt < 2; ++nt) b2f[nt] = w2v[krow * D + (w * 2 + nt) * 16 + m16];
#pragma unroll
    for (int mt = 0; mt < 4; ++mt)
#pragma unroll
      for (int nt = 0; nt < 2; ++nt)
        acc2[mt][nt] = __builtin_amdgcn_mfma_f32_16x16x32_f16(a2[mt], b2f[nt], acc2[mt][nt], 0, 0, 0);
  }
  __syncthreads();

  // cand f32 -> LDS (stride 130 to dodge bank conflicts)
#pragma unroll
  for (int nt = 0; nt < 2; ++nt) {
    int n = (w * 2 + nt) * 16 + m16;
    float bv = b2[n];
#pragma unroll
    for (int mt = 0; mt < 4; ++mt)
#pragma unroll
      for (int r = 0; r < 4; ++r) {
        int m = mt * 16 + q * 4 + r;
        sbuf[m * 130 + n] = acc2[mt][nt][r] + bv;
      }
  }
  __syncthreads();

  // epilogue: 4 threads per edge row
  {
    int m = t >> 2, sub = t & 3;
    int e = eb + m;
    float ub = upd_base[e], rb = read_base[e];
    v4f cv[8];
    float dg = 0.f;
#pragma unroll
    for (int i = 0; i < 8; ++i) {
      int co = sub * 32 + i * 4;
      cv[i] = *(const v4f*)(sbuf + m * 130 + co);
      v4f wu = *(const v4f*)(Wupd + 400 + co);
      dg += cv[i][0] * wu[0] + cv[i][1] * wu[1] + cv[i][2] * wu[2] + cv[i][3] * wu[3];
    }
    dg += __shfl_xor(dg, 1);
    dg += __shfl_xor(dg, 2);
    float gt = 1.f / (1.f + expf(-(ub + dg)));
    float dr = 0.f;
#pragma unroll
    for (int i = 0; i < 8; ++i) {
      int co = sub * 32 + i * 4;
      v4f h4 = *(const v4f*)(hef + (long)e * D + co);
      v4f ef;
      ef[0] = gt * cv[i][0] + (1.f - gt) * h4[0];
      ef[1] = gt * cv[i][1] + (1.f - gt) * h4[1];
      ef[2] = gt * cv[i][2] + (1.f - gt) * h4[2];
      ef[3] = gt * cv[i][3] + (1.f - gt) * h4[3];
      *(v4f*)(out_ef + (long)e * D + co) = ef;
      v4f wr = *(const v4f*)(Wread + 256 + co);
      dr += ef[0] * wr[0] + ef[1] * wr[1] + ef[2] * wr[2] + ef[3] * wr[3];
    }
    dr += __shfl_xor(dr, 1);
    dr += __shfl_xor(dr, 2);
    if (sub == 0) read_logit[e] = rb + dr;
  }
}

// per-graph max, stage 1: block partials in LDS (no global atomics)
__global__ __launch_bounds__(256) void k_gmax(
    const float* __restrict__ read_logit, const int* __restrict__ gidx,
    unsigned* __restrict__ gpart) {
  __shared__ unsigned gm[NG];
  int t = threadIdx.x;
  if (t < NG) gm[t] = 0u;   // fkey of anything > 0
  __syncthreads();
  int base = blockIdx.x * 1250;
#pragma unroll
  for (int i = 0; i < 5; ++i) {
    int idx = i * 256 + t;
    if (idx < 1250) {
      int e = base + idx;
      atomicMax(&gm[gidx[e]], fkey(read_logit[e]));
    }
  }
  __syncthreads();
  if (t < NG) gpart[blockIdx.x * NG + t] = gm[t];
}

// per-graph max, stage 2: reduce 256 partials per graph
__global__ __launch_bounds__(64) void k_gmax2(
    const unsigned* __restrict__ gpart, float* __restrict__ m_graph) {
  int g = blockIdx.x, lane = threadIdx.x;
  unsigned k = 0u;
#pragma unroll
  for (int j = 0; j < 4; ++j) {
    unsigned v = gpart[(lane + 64 * j) * NG + g];
    k = (v > k) ? v : k;
  }
  for (int o = 32; o > 0; o >>= 1) {
    unsigned v = __shfl_xor(k, o);
    k = (v > k) ? v : k;
  }
  if (lane == 0) m_graph[g] = fdec(k);
}

// graph softmax accumulate: per-block LDS [64][128] partials -> private slab (no global atomics)
__global__ __launch_bounds__(256) void k_readout(
    const float* __restrict__ ef, const float* __restrict__ read_logit,
    const int* __restrict__ gidx, const float* __restrict__ m_graph,
    float* __restrict__ gp, float* __restrict__ sgp) {
  __shared__ float accg[NG * D];
  __shared__ float sg[NG];
  int t = threadIdx.x;
  for (int j = t; j < NG * D; j += 256) accg[j] = 0.f;
  if (t < NG) sg[t] = 0.f;
  __syncthreads();
  int base = blockIdx.x * 1250;
  int half = t >> 7, d = t & 127;
  for (int i = 0; i < 625; ++i) {
    int e = base + i * 2 + half;
    float l = read_logit[e];
    int g = gidx[e];
    float wv = expf(l - m_graph[g]);
    if (d == 0) atomicAdd(&sg[g], wv);
    atomicAdd(&accg[g * D + d], wv * ef[(long)e * D + d]);
  }
  __syncthreads();
  for (int j = t; j < NG * D; j += 256) gp[(size_t)blockIdx.x * (NG * D) + j] = accg[j];
  if (t < NG) sgp[blockIdx.x * NG + t] = sg[t];
}

// reduce slabs + confidence
__global__ __launch_bounds__(128) void k_conf(
    const float* __restrict__ gp, const float* __restrict__ sgp,
    const float* __restrict__ Wscore, const float* __restrict__ bscore,
    float* __restrict__ out_conf) {
  __shared__ float redS[2], redP[2];
  int g = blockIdx.x, t = threadIdx.x;
  float s = 0.f;
  for (int b = t; b < RB; b += 128) s += sgp[b * NG + g];
  for (int o = 32; o > 0; o >>= 1) s += __shfl_xor(s, o);
  if ((t & 63) == 0) redS[t >> 6] = s;
  __syncthreads();
  s = redS[0] + redS[1];
  float acc = 0.f;
  for (int b = 0; b < RB; ++b) acc += gp[(size_t)b * (NG * D) + g * D + t];
  float v = acc / (s + 1e-16f);
  float p = v * Wscore[t];
  for (int o = 32; o > 0; o >>= 1) p += __shfl_xor(p, o);
  if ((t & 63) == 0) redP[t >> 6] = p;
  __syncthreads();
  if (t == 0) out_conf[g] = 1.f / (1.f + expf(-(redP[0] + redP[1] + bscore[0])));
}

extern "C" void kernel_launch(void* const* d_in, const int* in_sizes, int n_in,
                              void* d_out, int out_size, void* d_ws, size_t ws_size,
                              hipStream_t stream) {
  const float* x = (const float*)d_in[0];
  const float* hef = (const float*)d_in[1];
  const float* attr = (const float*)d_in[2];
  const int* eidx = (const int*)d_in[3];
  const int* rol = eidx;
  const int* col = eidx + E_EDGES;
  const int* batch = (const int*)d_in[4];
  const float* Wagg = (const float*)d_in[6];
  const float* bagg = (const float*)d_in[7];
  const float* W1 = (const float*)d_in[8];
  const float* b1 = (const float*)d_in[9];
  const float* W2 = (const float*)d_in[10];
  const float* b2 = (const float*)d_in[11];
  const float* Wupd = (const float*)d_in[12];
  const float* bupd = (const float*)d_in[13];
  const float* Wread = (const float*)d_in[14];
  const float* bread = (const float*)d_in[15];
  const float* Wscore = (const float*)d_in[16];
  const float* bscore = (const float*)d_in[17];

  char* ws = (char*)d_ws;
  size_t off = 0;
  auto alloc = [&](size_t bytes) -> void* {
    void* p = ws + off;
    off = (off + bytes + 255) & ~(size_t)255;
    return p;
  };

  // zero-initialized region first (single memset)
  int* deg = (int*)alloc(NN * 4);
  size_t zero_bytes = off;

  int* rowptr = (int*)alloc((NN + 1) * 4);
  int* cursor = (int*)alloc(NN * 4);
  int* csr = (int*)alloc((size_t)E_EDGES * 4);
  f16* xh = (f16*)alloc((size_t)NN * D * 2);
  f16* nfh = (f16*)alloc((size_t)NN * D * 2);
  f16* attrh = (f16*)alloc((size_t)E_EDGES * 32 * 2);
  f16* W1s = (f16*)alloc((size_t)K1PAD * HID * 2);
  f16* W2s = (f16*)alloc((size_t)HID * D * 2);
  float* na1 = (float*)alloc(NN * 4);
  float* na2 = (float*)alloc(NN * 4);
  float* nu1 = (float*)alloc(NN * 4);
  float* nu2 = (float*)alloc(NN * 4);
  float* nr1 = (float*)alloc(NN * 4);
  float* nr2 = (float*)alloc(NN * 4);
  float* agg_logit = (float*)alloc((size_t)E_EDGES * 4);
  float* upd_base = (float*)alloc((size_t)E_EDGES * 4);
  float* read_base = (float*)alloc((size_t)E_EDGES * 4);
  float* read_logit = (float*)alloc((size_t)E_EDGES * 4);
  int* gidx = (int*)alloc((size_t)E_EDGES * 4);
  unsigned* gpart = (unsigned*)alloc((size_t)RB * NG * 4);
  float* m_graph = (float*)alloc(NG * 4);
  float* gp = (float*)alloc((size_t)RB * NG * D * 4);
  float* sgp = (float*)alloc((size_t)RB * NG * 4);

  float* out_ef = (float*)d_out;
  float* out_conf = out_ef + (size_t)E_EDGES * D;

  hipMemsetAsync(d_ws, 0, zero_bytes, stream);
  k_prep_nodes<<<NN / 4, 256, 0, stream>>>(x, Wagg, Wupd, Wread, xh, na1, na2, nu1, nu2, nr1, nr2);
  k_prep_w<<<K1PAD + HID, 256, 0, stream>>>(W1, W2, W1s, W2s);
  k_prep_edges<<<E_EDGES / 4, 256, 0, stream>>>(hef, attr, rol, col, batch,
      Wagg, bagg, Wupd, bupd, Wread, bread,
      na1, na2, nu1, nu2, nr1, nr2,
      agg_logit, upd_base, read_base, gidx, deg, attrh);
  k_scan<<<1, 1024, 0, stream>>>(deg, rowptr, cursor);
  k_csr_fill<<<E_EDGES / 256, 256, 0, stream>>>(col, cursor, csr);
  k_node_feat<<<NN / 4, 256, 0, stream>>>(rowptr, csr, agg_logit, hef, nfh);
  k_mlp<<<E_EDGES / 64, 256, 0, stream>>>(xh, nfh, attrh, W1s, W2s, b1, b2,
      rol, col, hef, Wupd, Wread, upd_base, read_base,
      out_ef, read_logit);
  k_gmax<<<RB, 256, 0, stream>>>(read_logit, gidx, gpart);
  k_gmax2<<<NG, 64, 0, stream>>>(gpart, m_graph);
  k_readout<<<RB, 256, 0, stream>>>(out_ef, read_logit, gidx, m_graph, gp, sgp);
  k_conf<<<NG, 128, 0, stream>>>(gp, sgp, Wscore, bscore, out_conf);
}